// Round 5
// baseline (150.339 us; speedup 1.0000x reference)
//
#include <hip/hip_runtime.h>
#include <hip/hip_bf16.h>
#include <math.h>

#define NB 16
#define ND 512
#define NN 2048
#define NKF 32       // feature width K
#define NNK 65536    // N*K

typedef short s8v __attribute__((ext_vector_type(8)));
typedef float f4v __attribute__((ext_vector_type(4)));
typedef unsigned short u16;
typedef unsigned int u32;
typedef u16 u16x8 __attribute__((ext_vector_type(8)));
typedef u32 u32x4 __attribute__((ext_vector_type(4)));

__device__ __forceinline__ u16 f2bf(float x) {
    u32 u = __builtin_bit_cast(u32, x);
    return (u16)((u + 0x7fffu + ((u >> 16) & 1u)) >> 16);
}
__device__ __forceinline__ float bf2f(u16 b) {
    u32 u = ((u32)b) << 16;
    return __builtin_bit_cast(float, u);
}

__device__ __forceinline__ void gload_lds16(const void* g, void* l) {
    __builtin_amdgcn_global_load_lds(
        (const __attribute__((address_space(1))) void*)g,
        (__attribute__((address_space(3))) void*)l, 16, 0, 0);
}

// ---------------- Kernel 1: QKV projection via global_load_lds pipeline --------
// grid (64, 3, 4), block 256 (4 waves). Block = 4KB j-panel x 128 d-rows,
// processed in 16 chunks of 8 rows (32KB). Double-buffered LDS stage via
// global_load_lds width=16 with COUNTED vmcnt(8) (never 0 mid-loop): 2 chunks
// = 64KB/block continuously in flight -> MLP independent of VGPRs/waves.
// x staged once in LDS (broadcast float4 reads; no s_load sK$ thrash).
__global__ __launch_bounds__(256) void proj_partial(
    const float* __restrict__ x,
    const float* __restrict__ WQ, const float* __restrict__ WK,
    const float* __restrict__ WV, u16* __restrict__ part)
{
    const int t = threadIdx.x;
    const int w = t >> 6;            // wave 0..3
    const int lane = t & 63;
    const int jb = blockIdx.x;       // 0..63
    const int mat = blockIdx.y;      // 0..2
    const int dz = blockIdx.z;       // 0..3
    const float* __restrict__ W = (mat == 0) ? WQ : (mat == 1) ? WK : WV;
    const int j0 = jb * 1024;
    const int d0 = dz * 128;

    __shared__ __align__(16) float Wstage[2][8][1024];   // 64 KB double buffer
    __shared__ __align__(16) float xs[128][16];          // 8 KB, xs[d][b]

    // stage x slice once: xs[d][b] = x[b][d0+d]
    for (int i = t; i < 2048; i += 256) {
        int b = i & 15, d = i >> 4;
        xs[d][b] = x[b * ND + d0 + d];
    }

    float4 acc[16];
    #pragma unroll
    for (int b = 0; b < 16; b++) acc[b] = make_float4(0.f, 0.f, 0.f, 0.f);

    const int NCHUNK = 16;
    // stage(c, buf): wave w loads rows w*2, w*2+1 of the 8x1024 chunk,
    // 8 calls x 1KB (64 lanes x 16B), LDS dest wave-uniform + lane*16.
    auto stage = [&](int c, int buf) {
        const float* cbase = W + (size_t)(d0 + c * 8) * NNK + j0;
        #pragma unroll
        for (int s = 0; s < 8; s++) {
            int r = w * 2 + (s >> 2);
            int colq = (s & 3) * 256;
            const float* src = cbase + (size_t)r * NNK + colq + lane * 4;
            void* dst = (void*)&Wstage[buf][r][colq];
            gload_lds16(src, dst);
        }
    };

    stage(0, 0);
    stage(1, 1);

    #pragma unroll 1
    for (int c = 0; c < NCHUNK; c++) {
        const int buf = c & 1;
        // barrier1: chunk c staged (counted wait: keep c+1 in flight)
        if (c + 1 < NCHUNK) {
            asm volatile("s_waitcnt vmcnt(8) lgkmcnt(0)" ::: "memory");
        } else {
            asm volatile("s_waitcnt vmcnt(0) lgkmcnt(0)" ::: "memory");
        }
        __builtin_amdgcn_sched_barrier(0);
        __builtin_amdgcn_s_barrier();
        __builtin_amdgcn_sched_barrier(0);

        // compute chunk c: 8 rows
        #pragma unroll
        for (int r = 0; r < 8; r++) {
            const int dd = c * 8 + r;
            float xv[16];
            #pragma unroll
            for (int q = 0; q < 4; q++)
                *(float4*)&xv[q * 4] = *(const float4*)&xs[dd][q * 4];
            float4 wv = *(const float4*)&Wstage[buf][r][t * 4];
            #pragma unroll
            for (int b = 0; b < 16; b++) {
                acc[b].x = fmaf(xv[b], wv.x, acc[b].x);
                acc[b].y = fmaf(xv[b], wv.y, acc[b].y);
                acc[b].z = fmaf(xv[b], wv.z, acc[b].z);
                acc[b].w = fmaf(xv[b], wv.w, acc[b].w);
            }
        }

        // barrier2: all waves done reading buf before restaging it
        asm volatile("s_waitcnt lgkmcnt(0)" ::: "memory");
        __builtin_amdgcn_sched_barrier(0);
        __builtin_amdgcn_s_barrier();
        __builtin_amdgcn_sched_barrier(0);

        if (c + 2 < NCHUNK) stage(c + 2, buf);
    }

    // store bf16 partials: part[(mat*4+dz)*16 + b][j0 + t*4 ..]
    size_t base = ((size_t)(mat * 4 + dz) * 16) * NNK + j0 + t * 4;
    #pragma unroll
    for (int b = 0; b < 16; b++) {
        u32 lo = (u32)f2bf(acc[b].x) | ((u32)f2bf(acc[b].y) << 16);
        u32 hi = (u32)f2bf(acc[b].z) | ((u32)f2bf(acc[b].w) << 16);
        *(uint2*)(part + base + (size_t)b * NNK) = make_uint2(lo, hi);
    }
}

// ---------------- Kernel 2: reduce 4 partials + bias, cast bf16; V transposed ----
// grid (32, 16, 3), block 256. K gets softmax scale folded in (base-2 domain).
__global__ __launch_bounds__(256) void reduce_cast(
    const u16* __restrict__ part,
    const float* __restrict__ bQ, const float* __restrict__ bK,
    const float* __restrict__ bV,
    u16* __restrict__ qb, u16* __restrict__ kb, u16* __restrict__ vT)
{
    const int t = threadIdx.x;
    const int jc = blockIdx.x;    // 0..31  (chunk of 2048 flat cols)
    const int b  = blockIdx.y;    // 0..15
    const int mat = blockIdx.z;   // 0..2
    const float* __restrict__ bias = (mat == 0) ? bQ : (mat == 1) ? bK : bV;
    const int j = jc * 2048 + t * 8;

    float4 b0 = *(const float4*)(bias + j);
    float4 b1 = *(const float4*)(bias + j + 4);
    float v[8] = {b0.x, b0.y, b0.z, b0.w, b1.x, b1.y, b1.z, b1.w};

    #pragma unroll
    for (int dz = 0; dz < 4; dz++) {
        size_t p = ((size_t)(mat * 4 + dz) * 16 + b) * NNK + j;
        u16x8 pp = *(const u16x8*)(part + p);
        #pragma unroll
        for (int i = 0; i < 8; i++) v[i] += bf2f(pp[i]);
    }

    const float scale = (mat == 1) ? 0.2550868230023389f : 1.0f; // log2(e)/sqrt(32)
    u16 h[8];
    #pragma unroll
    for (int i = 0; i < 8; i++) h[i] = f2bf(v[i] * scale);

    __shared__ u16 vt[32][72];  // padded transpose tile

    if (mat < 2) {
        u16* dst = ((mat == 0) ? qb : kb) + (size_t)b * NNK + j;
        u16x8 hv;
        #pragma unroll
        for (int i = 0; i < 8; i++) hv[i] = h[i];
        *(u16x8*)dst = hv;
    } else {
        const int n  = t >> 2;          // 0..63 local point
        const int k0 = (t & 3) * 8;     // feature start
        #pragma unroll
        for (int i = 0; i < 8; i++) vt[k0 + i][n] = h[i];
        __syncthreads();
        const int k  = t >> 3;          // 0..31
        const int c8 = t & 7;           // 0..7
        u16x8 ov;
        #pragma unroll
        for (int i = 0; i < 8; i++) ov[i] = vt[k][c8 * 8 + i];
        u16* dst = vT + (size_t)b * NNK + (size_t)k * NN + jc * 64 + c8 * 8;
        *(u16x8*)dst = ov;
    }
}

// ---------------- Kernel 3: fused flash attention + output/ori projection --------
// grid (32, 16), block 256 (4 waves x 16 q-rows). KVBLK=64, double-buffered LDS.
__global__ __launch_bounds__(256) void attn_kernel(
    const u16* __restrict__ qb, const u16* __restrict__ kb,
    const u16* __restrict__ vT,
    const float* __restrict__ Wout, const float* __restrict__ bout,
    const float* __restrict__ Wori, const float* __restrict__ bori,
    float* __restrict__ out)
{
    const int t = threadIdx.x;
    const int w = t >> 6;
    const int l = t & 63;
    const int g = l >> 4;
    const int n = l & 15;
    const int b = blockIdx.y;
    const int q0 = blockIdx.x * 64;

    __shared__ __align__(16) u16 Ks[2][2048];   // [64 kv][32 k] row-major
    __shared__ __align__(16) u16 Vs[2][2048];   // [32 dk][64 kv], col16 XOR-swizzled

    // Q fragment (B-operand of swapped QK^T): row q0+w*16+n, k = g*8..g*8+7
    const u16* qrow = qb + (size_t)b * NNK + (size_t)(q0 + w * 16 + n) * NKF + g * 8;
    const s8v qf = *(const s8v*)qrow;

    // staging addresses
    const int krow = t >> 2, kcol = (t & 3) * 8;
    const int vrow = t >> 3, vslot = t & 7;
    const int vcolL = (vslot ^ (vrow & 7)) * 8;   // pre-swizzled global column
    const u16* kgp = kb + (size_t)b * NNK + (size_t)krow * NKF + kcol;
    const u16* vgp = vT + (size_t)b * NNK + (size_t)vrow * NN + vcolL;

    s8v kreg, vreg;
    // tile 0 -> LDS buf0; tile 1 -> regs
    kreg = *(const s8v*)(kgp);                 vreg = *(const s8v*)(vgp);
    *(s8v*)(&Ks[0][t * 8]) = kreg;             *(s8v*)(&Vs[0][t * 8]) = vreg;
    kreg = *(const s8v*)(kgp + (size_t)2048);  vreg = *(const s8v*)(vgp + 64);
    __syncthreads();

    float m_run = -INFINITY, l_run = 0.f;
    f4v O0 = {0.f, 0.f, 0.f, 0.f}, O1 = {0.f, 0.f, 0.f, 0.f};
    const bool hi = (l >= 32);
    const int srcA = ((2 * g) & 3) * 16 + n;
    const int srcB = ((2 * g + 1) & 3) * 16 + n;

    for (int it = 0; it < 32; it++) {
        const int cur = it & 1;
        if (it + 1 < 32) {   // write tile it+1 from regs into the other buffer
            *(s8v*)(&Ks[cur ^ 1][t * 8]) = kreg;
            *(s8v*)(&Vs[cur ^ 1][t * 8]) = vreg;
        }
        if (it + 2 < 32) {   // prefetch tile it+2 into regs
            kreg = *(const s8v*)(kgp + (size_t)(it + 2) * 2048);
            vreg = *(const s8v*)(vgp + (size_t)(it + 2) * 64);
        }

        // ---- QK^T (swapped): S^T tiles, lane holds 16 scores for q-row n ----
        f4v S[4];
        #pragma unroll
        for (int tt = 0; tt < 4; tt++) {
            s8v ka = *(const s8v*)(&Ks[cur][(n + 16 * tt) * NKF + g * 8]);
            f4v z = {0.f, 0.f, 0.f, 0.f};
            S[tt] = __builtin_amdgcn_mfma_f32_16x16x32_bf16(ka, qf, z, 0, 0, 0);
        }

        // ---- online softmax in base-2 (scale folded into k) ----
        float pmax = -INFINITY;
        #pragma unroll
        for (int tt = 0; tt < 4; tt++)
            #pragma unroll
            for (int r = 0; r < 4; r++) pmax = fmaxf(pmax, S[tt][r]);
        pmax = fmaxf(pmax, __shfl_xor(pmax, 16));
        pmax = fmaxf(pmax, __shfl_xor(pmax, 32));
        const float m_new = fmaxf(m_run, pmax);
        const float corr = exp2f(m_run - m_new);

        float p[4][4];
        float tsum = 0.f;
        #pragma unroll
        for (int tt = 0; tt < 4; tt++)
            #pragma unroll
            for (int r = 0; r < 4; r++) {
                p[tt][r] = exp2f(S[tt][r] - m_new);
                tsum += p[tt][r];
            }
        tsum += __shfl_xor(tsum, 16);
        tsum += __shfl_xor(tsum, 32);
        l_run = l_run * corr + tsum;
        m_run = m_new;
        #pragma unroll
        for (int r = 0; r < 4; r++) { O0[r] *= corr; O1[r] *= corr; }

        // ---- pack P to bf16 pairs: pk[tt][j] covers kv = 16tt+4g+{2j,2j+1} ----
        u32 pk[4][2];
        #pragma unroll
        for (int tt = 0; tt < 4; tt++) {
            pk[tt][0] = (u32)f2bf(p[tt][0]) | ((u32)f2bf(p[tt][1]) << 16);
            pk[tt][1] = (u32)f2bf(p[tt][2]) | ((u32)f2bf(p[tt][3]) << 16);
        }

        // ---- shuffle to PV B-operand (P^T), then O^T += V^T * P^T ----
        #pragma unroll
        for (int kc = 0; kc < 2; kc++) {
            u32 lo0 = (u32)__shfl((int)pk[2 * kc][0], srcA);
            u32 hi0 = (u32)__shfl((int)pk[2 * kc + 1][0], srcA);
            u32 lo1 = (u32)__shfl((int)pk[2 * kc][1], srcA);
            u32 hi1 = (u32)__shfl((int)pk[2 * kc + 1][1], srcA);
            u32 lo2 = (u32)__shfl((int)pk[2 * kc][0], srcB);
            u32 hi2 = (u32)__shfl((int)pk[2 * kc + 1][0], srcB);
            u32 lo3 = (u32)__shfl((int)pk[2 * kc][1], srcB);
            u32 hi3 = (u32)__shfl((int)pk[2 * kc + 1][1], srcB);
            u32x4 fr;
            fr.x = hi ? hi0 : lo0;
            fr.y = hi ? hi1 : lo1;
            fr.z = hi ? hi2 : lo2;
            fr.w = hi ? hi3 : lo3;
            s8v pa = __builtin_bit_cast(s8v, fr);

            {   // dt = 0
                int row = n;
                int slot = (g + 4 * kc) ^ (row & 7);
                s8v va = *(const s8v*)(&Vs[cur][row * 64 + slot * 8]);
                O0 = __builtin_amdgcn_mfma_f32_16x16x32_bf16(va, pa, O0, 0, 0, 0);
            }
            {   // dt = 1
                int row = n + 16;
                int slot = (g + 4 * kc) ^ (row & 7);
                s8v va = *(const s8v*)(&Vs[cur][row * 64 + slot * 8]);
                O1 = __builtin_amdgcn_mfma_f32_16x16x32_bf16(va, pa, O1, 0, 0, 0);
            }
        }
        __syncthreads();
    }

    // ---- epilogue: out = O/l * Wout^T + q * Wori^T + bout + bori ----
    const float inv = 1.0f / l_run;
    float po[3] = {0.f, 0.f, 0.f};
    #pragma unroll
    for (int r = 0; r < 4; r++) {
        int dk0 = 4 * g + r;
        int dk1 = 16 + 4 * g + r;
        float o0 = O0[r] * inv;
        float o1 = O1[r] * inv;
        #pragma unroll
        for (int c = 0; c < 3; c++) {
            po[c] += o0 * Wout[c * NKF + dk0];
            po[c] += o1 * Wout[c * NKF + dk1];
        }
    }
    #pragma unroll
    for (int e = 0; e < 8; e++) {
        float qv = bf2f((u16)qf[e]);
        int k = 8 * g + e;
        #pragma unroll
        for (int c = 0; c < 3; c++) po[c] += qv * Wori[c * NKF + k];
    }
    #pragma unroll
    for (int c = 0; c < 3; c++) {
        po[c] += __shfl_xor(po[c], 16);
        po[c] += __shfl_xor(po[c], 32);
    }
    if (g == 0) {
        int row = q0 + w * 16 + n;
        size_t o = ((size_t)b * NN + row) * 3;
        #pragma unroll
        for (int c = 0; c < 3; c++) out[o + c] = po[c] + bout[c] + bori[c];
    }
}

// ---------------- launch ----------------
extern "C" void kernel_launch(void* const* d_in, const int* in_sizes, int n_in,
                              void* d_out, int out_size, void* d_ws, size_t ws_size,
                              hipStream_t stream) {
    const float* x    = (const float*)d_in[0];
    const float* WQ   = (const float*)d_in[1];
    const float* bQ   = (const float*)d_in[2];
    const float* WK   = (const float*)d_in[3];
    const float* bK   = (const float*)d_in[4];
    const float* WV   = (const float*)d_in[5];
    const float* bV   = (const float*)d_in[6];
    const float* Wout = (const float*)d_in[7];
    const float* bout = (const float*)d_in[8];
    const float* Wori = (const float*)d_in[9];
    const float* bori = (const float*)d_in[10];
    float* out = (float*)d_out;

    char* ws = (char*)d_ws;
    u16* part = (u16*)ws;                              // 3*4*16*65536*2 = 25165824 B
    u16* qb = (u16*)(ws + 25165824);                   // 2 MB
    u16* kb = (u16*)(ws + 25165824 + 2097152);         // 2 MB
    u16* vT = (u16*)(ws + 25165824 + 2 * 2097152);     // 2 MB

    proj_partial<<<dim3(64, 3, 4), 256, 0, stream>>>(x, WQ, WK, WV, part);
    reduce_cast<<<dim3(32, 16, 3), 256, 0, stream>>>(part, bQ, bK, bV, qb, kb, vT);
    attn_kernel<<<dim3(32, 16), 256, 0, stream>>>(qb, kb, vT, Wout, bout, Wori, bori, out);
}

// Round 6
// 133.587 us; speedup vs baseline: 1.1254x; 1.1254x over previous
//
#include <hip/hip_runtime.h>
#include <hip/hip_bf16.h>
#include <math.h>

#define NB 16
#define ND 512
#define NN 2048
#define NKF 32       // feature width K
#define NNK 65536    // N*K

typedef short s8v __attribute__((ext_vector_type(8)));
typedef float f4v __attribute__((ext_vector_type(4)));
typedef unsigned short u16;
typedef unsigned int u32;
typedef u16 u16x8 __attribute__((ext_vector_type(8)));
typedef u32 u32x4 __attribute__((ext_vector_type(4)));

__device__ __forceinline__ u16 f2bf(float x) {
    u32 u = __builtin_bit_cast(u32, x);
    return (u16)((u + 0x7fffu + ((u >> 16) & 1u)) >> 16);
}
__device__ __forceinline__ float bf2f(u16 b) {
    u32 u = ((u32)b) << 16;
    return __builtin_bit_cast(float, u);
}

// ---------------- Kernel 1: QKV projection, NON-TEMPORAL W loads ----------------
// Identical to R4 (float4 panels, grid (64,3,4), 8-row ping-pong, scalar x)
// EXCEPT W is loaded with __builtin_nontemporal_load (global_load_dwordx4 nt).
// Discriminator: if the ~3 TB/s read wall is per-CU L1/TCP miss tracking, nt
// streaming loads lift it; if it's the XCD fabric read path, no change and
// 402MB/3TB/s = 134us is the structural roofline (matches all 5 variants).
__global__ __launch_bounds__(256) void proj_partial(
    const float* __restrict__ x,
    const float* __restrict__ WQ, const float* __restrict__ WK,
    const float* __restrict__ WV, u16* __restrict__ part)
{
    const int t = threadIdx.x;
    const int jb = blockIdx.x;       // 0..63
    const int mat = blockIdx.y;      // 0..2
    const int dz = blockIdx.z;       // 0..3
    const float* __restrict__ W = (mat == 0) ? WQ : (mat == 1) ? WK : WV;
    const int j = jb * 1024 + t * 4;
    const int d0 = dz * 128;

    f4v acc[16];
    #pragma unroll
    for (int b = 0; b < 16; b++) acc[b] = (f4v){0.f, 0.f, 0.f, 0.f};

    const float* wp = W + (size_t)d0 * NNK + j;
    const float* xp = x + d0;        // xp[b*ND + dd] is wave-uniform -> s_load

    f4v wa[8], wb[8];
    #pragma unroll
    for (int u = 0; u < 8; u++)
        wa[u] = __builtin_nontemporal_load((const f4v*)(wp + (size_t)u * NNK));

    #pragma unroll 1
    for (int dd = 0; dd < 128; dd += 16) {
        // prefetch rows dd+8..dd+15 into wb, pinned above the wa compute
        #pragma unroll
        for (int u = 0; u < 8; u++)
            wb[u] = __builtin_nontemporal_load(
                (const f4v*)(wp + (size_t)(dd + 8 + u) * NNK));
        __builtin_amdgcn_sched_barrier(0);

        // compute rows dd..dd+7 from wa (x via uniform scalar loads)
        #pragma unroll
        for (int u = 0; u < 8; u++) {
            const float* xr = xp + dd + u;
            #pragma unroll
            for (int b = 0; b < 16; b++) {
                float xv = xr[b * ND];
                acc[b][0] = fmaf(xv, wa[u][0], acc[b][0]);
                acc[b][1] = fmaf(xv, wa[u][1], acc[b][1]);
                acc[b][2] = fmaf(xv, wa[u][2], acc[b][2]);
                acc[b][3] = fmaf(xv, wa[u][3], acc[b][3]);
            }
        }

        // prefetch rows dd+16..dd+23 into wa, pinned above the wb compute
        if (dd + 16 < 128) {
            #pragma unroll
            for (int u = 0; u < 8; u++)
                wa[u] = __builtin_nontemporal_load(
                    (const f4v*)(wp + (size_t)(dd + 16 + u) * NNK));
        }
        __builtin_amdgcn_sched_barrier(0);

        // compute rows dd+8..dd+15 from wb
        #pragma unroll
        for (int u = 0; u < 8; u++) {
            const float* xr = xp + dd + 8 + u;
            #pragma unroll
            for (int b = 0; b < 16; b++) {
                float xv = xr[b * ND];
                acc[b][0] = fmaf(xv, wb[u][0], acc[b][0]);
                acc[b][1] = fmaf(xv, wb[u][1], acc[b][1]);
                acc[b][2] = fmaf(xv, wb[u][2], acc[b][2]);
                acc[b][3] = fmaf(xv, wb[u][3], acc[b][3]);
            }
        }
    }

    // store bf16 partials: part[(mat*4+dz)*16 + b][j..j+3]
    size_t base = ((size_t)(mat * 4 + dz) * 16) * NNK + j;
    #pragma unroll
    for (int b = 0; b < 16; b++) {
        u32 lo = (u32)f2bf(acc[b][0]) | ((u32)f2bf(acc[b][1]) << 16);
        u32 hi = (u32)f2bf(acc[b][2]) | ((u32)f2bf(acc[b][3]) << 16);
        *(uint2*)(part + base + (size_t)b * NNK) = make_uint2(lo, hi);
    }
}

// ---------------- Kernel 2: reduce 4 partials + bias, cast bf16; V transposed ----
// grid (32, 16, 3), block 256. K gets softmax scale folded in (base-2 domain).
__global__ __launch_bounds__(256) void reduce_cast(
    const u16* __restrict__ part,
    const float* __restrict__ bQ, const float* __restrict__ bK,
    const float* __restrict__ bV,
    u16* __restrict__ qb, u16* __restrict__ kb, u16* __restrict__ vT)
{
    const int t = threadIdx.x;
    const int jc = blockIdx.x;    // 0..31  (chunk of 2048 flat cols)
    const int b  = blockIdx.y;    // 0..15
    const int mat = blockIdx.z;   // 0..2
    const float* __restrict__ bias = (mat == 0) ? bQ : (mat == 1) ? bK : bV;
    const int j = jc * 2048 + t * 8;

    float4 b0 = *(const float4*)(bias + j);
    float4 b1 = *(const float4*)(bias + j + 4);
    float v[8] = {b0.x, b0.y, b0.z, b0.w, b1.x, b1.y, b1.z, b1.w};

    #pragma unroll
    for (int dz = 0; dz < 4; dz++) {
        size_t p = ((size_t)(mat * 4 + dz) * 16 + b) * NNK + j;
        u16x8 pp = *(const u16x8*)(part + p);
        #pragma unroll
        for (int i = 0; i < 8; i++) v[i] += bf2f(pp[i]);
    }

    const float scale = (mat == 1) ? 0.2550868230023389f : 1.0f; // log2(e)/sqrt(32)
    u16 h[8];
    #pragma unroll
    for (int i = 0; i < 8; i++) h[i] = f2bf(v[i] * scale);

    __shared__ u16 vt[32][72];  // padded transpose tile

    if (mat < 2) {
        u16* dst = ((mat == 0) ? qb : kb) + (size_t)b * NNK + j;
        u16x8 hv;
        #pragma unroll
        for (int i = 0; i < 8; i++) hv[i] = h[i];
        *(u16x8*)dst = hv;
    } else {
        const int n  = t >> 2;          // 0..63 local point
        const int k0 = (t & 3) * 8;     // feature start
        #pragma unroll
        for (int i = 0; i < 8; i++) vt[k0 + i][n] = h[i];
        __syncthreads();
        const int k  = t >> 3;          // 0..31
        const int c8 = t & 7;           // 0..7
        u16x8 ov;
        #pragma unroll
        for (int i = 0; i < 8; i++) ov[i] = vt[k][c8 * 8 + i];
        u16* dst = vT + (size_t)b * NNK + (size_t)k * NN + jc * 64 + c8 * 8;
        *(u16x8*)dst = ov;
    }
}

// ---------------- Kernel 3: fused flash attention + output/ori projection --------
// grid (32, 16), block 256 (4 waves x 16 q-rows). KVBLK=64, double-buffered LDS.
__global__ __launch_bounds__(256) void attn_kernel(
    const u16* __restrict__ qb, const u16* __restrict__ kb,
    const u16* __restrict__ vT,
    const float* __restrict__ Wout, const float* __restrict__ bout,
    const float* __restrict__ Wori, const float* __restrict__ bori,
    float* __restrict__ out)
{
    const int t = threadIdx.x;
    const int w = t >> 6;
    const int l = t & 63;
    const int g = l >> 4;
    const int n = l & 15;
    const int b = blockIdx.y;
    const int q0 = blockIdx.x * 64;

    __shared__ __align__(16) u16 Ks[2][2048];   // [64 kv][32 k] row-major
    __shared__ __align__(16) u16 Vs[2][2048];   // [32 dk][64 kv], col16 XOR-swizzled

    // Q fragment (B-operand of swapped QK^T): row q0+w*16+n, k = g*8..g*8+7
    const u16* qrow = qb + (size_t)b * NNK + (size_t)(q0 + w * 16 + n) * NKF + g * 8;
    const s8v qf = *(const s8v*)qrow;

    // staging addresses
    const int krow = t >> 2, kcol = (t & 3) * 8;
    const int vrow = t >> 3, vslot = t & 7;
    const int vcolL = (vslot ^ (vrow & 7)) * 8;   // pre-swizzled global column
    const u16* kgp = kb + (size_t)b * NNK + (size_t)krow * NKF + kcol;
    const u16* vgp = vT + (size_t)b * NNK + (size_t)vrow * NN + vcolL;

    s8v kreg, vreg;
    // tile 0 -> LDS buf0; tile 1 -> regs
    kreg = *(const s8v*)(kgp);                 vreg = *(const s8v*)(vgp);
    *(s8v*)(&Ks[0][t * 8]) = kreg;             *(s8v*)(&Vs[0][t * 8]) = vreg;
    kreg = *(const s8v*)(kgp + (size_t)2048);  vreg = *(const s8v*)(vgp + 64);
    __syncthreads();

    float m_run = -INFINITY, l_run = 0.f;
    f4v O0 = {0.f, 0.f, 0.f, 0.f}, O1 = {0.f, 0.f, 0.f, 0.f};
    const bool hi = (l >= 32);
    const int srcA = ((2 * g) & 3) * 16 + n;
    const int srcB = ((2 * g + 1) & 3) * 16 + n;

    for (int it = 0; it < 32; it++) {
        const int cur = it & 1;
        if (it + 1 < 32) {   // write tile it+1 from regs into the other buffer
            *(s8v*)(&Ks[cur ^ 1][t * 8]) = kreg;
            *(s8v*)(&Vs[cur ^ 1][t * 8]) = vreg;
        }
        if (it + 2 < 32) {   // prefetch tile it+2 into regs
            kreg = *(const s8v*)(kgp + (size_t)(it + 2) * 2048);
            vreg = *(const s8v*)(vgp + (size_t)(it + 2) * 64);
        }

        // ---- QK^T (swapped): S^T tiles, lane holds 16 scores for q-row n ----
        f4v S[4];
        #pragma unroll
        for (int tt = 0; tt < 4; tt++) {
            s8v ka = *(const s8v*)(&Ks[cur][(n + 16 * tt) * NKF + g * 8]);
            f4v z = {0.f, 0.f, 0.f, 0.f};
            S[tt] = __builtin_amdgcn_mfma_f32_16x16x32_bf16(ka, qf, z, 0, 0, 0);
        }

        // ---- online softmax in base-2 (scale folded into k) ----
        float pmax = -INFINITY;
        #pragma unroll
        for (int tt = 0; tt < 4; tt++)
            #pragma unroll
            for (int r = 0; r < 4; r++) pmax = fmaxf(pmax, S[tt][r]);
        pmax = fmaxf(pmax, __shfl_xor(pmax, 16));
        pmax = fmaxf(pmax, __shfl_xor(pmax, 32));
        const float m_new = fmaxf(m_run, pmax);
        const float corr = exp2f(m_run - m_new);

        float p[4][4];
        float tsum = 0.f;
        #pragma unroll
        for (int tt = 0; tt < 4; tt++)
            #pragma unroll
            for (int r = 0; r < 4; r++) {
                p[tt][r] = exp2f(S[tt][r] - m_new);
                tsum += p[tt][r];
            }
        tsum += __shfl_xor(tsum, 16);
        tsum += __shfl_xor(tsum, 32);
        l_run = l_run * corr + tsum;
        m_run = m_new;
        #pragma unroll
        for (int r = 0; r < 4; r++) { O0[r] *= corr; O1[r] *= corr; }

        // ---- pack P to bf16 pairs: pk[tt][j] covers kv = 16tt+4g+{2j,2j+1} ----
        u32 pk[4][2];
        #pragma unroll
        for (int tt = 0; tt < 4; tt++) {
            pk[tt][0] = (u32)f2bf(p[tt][0]) | ((u32)f2bf(p[tt][1]) << 16);
            pk[tt][1] = (u32)f2bf(p[tt][2]) | ((u32)f2bf(p[tt][3]) << 16);
        }

        // ---- shuffle to PV B-operand (P^T), then O^T += V^T * P^T ----
        #pragma unroll
        for (int kc = 0; kc < 2; kc++) {
            u32 lo0 = (u32)__shfl((int)pk[2 * kc][0], srcA);
            u32 hi0 = (u32)__shfl((int)pk[2 * kc + 1][0], srcA);
            u32 lo1 = (u32)__shfl((int)pk[2 * kc][1], srcA);
            u32 hi1 = (u32)__shfl((int)pk[2 * kc + 1][1], srcA);
            u32 lo2 = (u32)__shfl((int)pk[2 * kc][0], srcB);
            u32 hi2 = (u32)__shfl((int)pk[2 * kc + 1][0], srcB);
            u32 lo3 = (u32)__shfl((int)pk[2 * kc][1], srcB);
            u32 hi3 = (u32)__shfl((int)pk[2 * kc + 1][1], srcB);
            u32x4 fr;
            fr.x = hi ? hi0 : lo0;
            fr.y = hi ? hi1 : lo1;
            fr.z = hi ? hi2 : lo2;
            fr.w = hi ? hi3 : lo3;
            s8v pa = __builtin_bit_cast(s8v, fr);

            {   // dt = 0
                int row = n;
                int slot = (g + 4 * kc) ^ (row & 7);
                s8v va = *(const s8v*)(&Vs[cur][row * 64 + slot * 8]);
                O0 = __builtin_amdgcn_mfma_f32_16x16x32_bf16(va, pa, O0, 0, 0, 0);
            }
            {   // dt = 1
                int row = n + 16;
                int slot = (g + 4 * kc) ^ (row & 7);
                s8v va = *(const s8v*)(&Vs[cur][row * 64 + slot * 8]);
                O1 = __builtin_amdgcn_mfma_f32_16x16x32_bf16(va, pa, O1, 0, 0, 0);
            }
        }
        __syncthreads();
    }

    // ---- epilogue: out = O/l * Wout^T + q * Wori^T + bout + bori ----
    const float inv = 1.0f / l_run;
    float po[3] = {0.f, 0.f, 0.f};
    #pragma unroll
    for (int r = 0; r < 4; r++) {
        int dk0 = 4 * g + r;
        int dk1 = 16 + 4 * g + r;
        float o0 = O0[r] * inv;
        float o1 = O1[r] * inv;
        #pragma unroll
        for (int c = 0; c < 3; c++) {
            po[c] += o0 * Wout[c * NKF + dk0];
            po[c] += o1 * Wout[c * NKF + dk1];
        }
    }
    #pragma unroll
    for (int e = 0; e < 8; e++) {
        float qv = bf2f((u16)qf[e]);
        int k = 8 * g + e;
        #pragma unroll
        for (int c = 0; c < 3; c++) po[c] += qv * Wori[c * NKF + k];
    }
    #pragma unroll
    for (int c = 0; c < 3; c++) {
        po[c] += __shfl_xor(po[c], 16);
        po[c] += __shfl_xor(po[c], 32);
    }
    if (g == 0) {
        int row = q0 + w * 16 + n;
        size_t o = ((size_t)b * NN + row) * 3;
        #pragma unroll
        for (int c = 0; c < 3; c++) out[o + c] = po[c] + bout[c] + bori[c];
    }
}

// ---------------- launch ----------------
extern "C" void kernel_launch(void* const* d_in, const int* in_sizes, int n_in,
                              void* d_out, int out_size, void* d_ws, size_t ws_size,
                              hipStream_t stream) {
    const float* x    = (const float*)d_in[0];
    const float* WQ   = (const float*)d_in[1];
    const float* bQ   = (const float*)d_in[2];
    const float* WK   = (const float*)d_in[3];
    const float* bK   = (const float*)d_in[4];
    const float* WV   = (const float*)d_in[5];
    const float* bV   = (const float*)d_in[6];
    const float* Wout = (const float*)d_in[7];
    const float* bout = (const float*)d_in[8];
    const float* Wori = (const float*)d_in[9];
    const float* bori = (const float*)d_in[10];
    float* out = (float*)d_out;

    char* ws = (char*)d_ws;
    u16* part = (u16*)ws;                              // 3*4*16*65536*2 = 25165824 B
    u16* qb = (u16*)(ws + 25165824);                   // 2 MB
    u16* kb = (u16*)(ws + 25165824 + 2097152);         // 2 MB
    u16* vT = (u16*)(ws + 25165824 + 2 * 2097152);     // 2 MB

    proj_partial<<<dim3(64, 3, 4), 256, 0, stream>>>(x, WQ, WK, WV, part);
    reduce_cast<<<dim3(32, 16, 3), 256, 0, stream>>>(part, bQ, bK, bV, qb, kb, vT);
    attn_kernel<<<dim3(32, 16), 256, 0, stream>>>(qb, kb, vT, Wout, bout, Wori, bori, out);
}

// Round 7
// 132.618 us; speedup vs baseline: 1.1336x; 1.0073x over previous
//
#include <hip/hip_runtime.h>
#include <hip/hip_bf16.h>
#include <math.h>

#define NB 16
#define ND 512
#define NN 2048
#define NKF 32       // feature width K
#define NNK 65536    // N*K

typedef short s8v __attribute__((ext_vector_type(8)));
typedef float f4v __attribute__((ext_vector_type(4)));
typedef unsigned short u16;
typedef unsigned int u32;
typedef u16 u16x8 __attribute__((ext_vector_type(8)));
typedef u32 u32x4 __attribute__((ext_vector_type(4)));

__device__ __forceinline__ u16 f2bf(float x) {
    u32 u = __builtin_bit_cast(u32, x);
    return (u16)((u + 0x7fffu + ((u >> 16) & 1u)) >> 16);
}
__device__ __forceinline__ float bf2f(u16 b) {
    u32 u = ((u32)b) << 16;
    return __builtin_bit_cast(float, u);
}

// ---------------- Kernel 1: QKV projection, NON-TEMPORAL W loads (R6, proven) ----
__global__ __launch_bounds__(256) void proj_partial(
    const float* __restrict__ x,
    const float* __restrict__ WQ, const float* __restrict__ WK,
    const float* __restrict__ WV, u16* __restrict__ part)
{
    const int t = threadIdx.x;
    const int jb = blockIdx.x;       // 0..63
    const int mat = blockIdx.y;      // 0..2
    const int dz = blockIdx.z;       // 0..3
    const float* __restrict__ W = (mat == 0) ? WQ : (mat == 1) ? WK : WV;
    const int j = jb * 1024 + t * 4;
    const int d0 = dz * 128;

    f4v acc[16];
    #pragma unroll
    for (int b = 0; b < 16; b++) acc[b] = (f4v){0.f, 0.f, 0.f, 0.f};

    const float* wp = W + (size_t)d0 * NNK + j;
    const float* xp = x + d0;        // xp[b*ND + dd] is wave-uniform -> s_load

    f4v wa[8], wb[8];
    #pragma unroll
    for (int u = 0; u < 8; u++)
        wa[u] = __builtin_nontemporal_load((const f4v*)(wp + (size_t)u * NNK));

    #pragma unroll 1
    for (int dd = 0; dd < 128; dd += 16) {
        #pragma unroll
        for (int u = 0; u < 8; u++)
            wb[u] = __builtin_nontemporal_load(
                (const f4v*)(wp + (size_t)(dd + 8 + u) * NNK));
        __builtin_amdgcn_sched_barrier(0);

        #pragma unroll
        for (int u = 0; u < 8; u++) {
            const float* xr = xp + dd + u;
            #pragma unroll
            for (int b = 0; b < 16; b++) {
                float xv = xr[b * ND];
                acc[b][0] = fmaf(xv, wa[u][0], acc[b][0]);
                acc[b][1] = fmaf(xv, wa[u][1], acc[b][1]);
                acc[b][2] = fmaf(xv, wa[u][2], acc[b][2]);
                acc[b][3] = fmaf(xv, wa[u][3], acc[b][3]);
            }
        }

        if (dd + 16 < 128) {
            #pragma unroll
            for (int u = 0; u < 8; u++)
                wa[u] = __builtin_nontemporal_load(
                    (const f4v*)(wp + (size_t)(dd + 16 + u) * NNK));
        }
        __builtin_amdgcn_sched_barrier(0);

        #pragma unroll
        for (int u = 0; u < 8; u++) {
            const float* xr = xp + dd + 8 + u;
            #pragma unroll
            for (int b = 0; b < 16; b++) {
                float xv = xr[b * ND];
                acc[b][0] = fmaf(xv, wb[u][0], acc[b][0]);
                acc[b][1] = fmaf(xv, wb[u][1], acc[b][1]);
                acc[b][2] = fmaf(xv, wb[u][2], acc[b][2]);
                acc[b][3] = fmaf(xv, wb[u][3], acc[b][3]);
            }
        }
    }

    size_t base = ((size_t)(mat * 4 + dz) * 16) * NNK + j;
    #pragma unroll
    for (int b = 0; b < 16; b++) {
        u32 lo = (u32)f2bf(acc[b][0]) | ((u32)f2bf(acc[b][1]) << 16);
        u32 hi = (u32)f2bf(acc[b][2]) | ((u32)f2bf(acc[b][3]) << 16);
        *(uint2*)(part + base + (size_t)b * NNK) = make_uint2(lo, hi);
    }
}

// ---------------- Kernel 2: reduce 4 partials + bias, cast bf16; V transposed ----
__global__ __launch_bounds__(256) void reduce_cast(
    const u16* __restrict__ part,
    const float* __restrict__ bQ, const float* __restrict__ bK,
    const float* __restrict__ bV,
    u16* __restrict__ qb, u16* __restrict__ kb, u16* __restrict__ vT)
{
    const int t = threadIdx.x;
    const int jc = blockIdx.x;    // 0..31
    const int b  = blockIdx.y;    // 0..15
    const int mat = blockIdx.z;   // 0..2
    const float* __restrict__ bias = (mat == 0) ? bQ : (mat == 1) ? bK : bV;
    const int j = jc * 2048 + t * 8;

    float4 b0 = *(const float4*)(bias + j);
    float4 b1 = *(const float4*)(bias + j + 4);
    float v[8] = {b0.x, b0.y, b0.z, b0.w, b1.x, b1.y, b1.z, b1.w};

    #pragma unroll
    for (int dz = 0; dz < 4; dz++) {
        size_t p = ((size_t)(mat * 4 + dz) * 16 + b) * NNK + j;
        u16x8 pp = *(const u16x8*)(part + p);
        #pragma unroll
        for (int i = 0; i < 8; i++) v[i] += bf2f(pp[i]);
    }

    const float scale = (mat == 1) ? 0.2550868230023389f : 1.0f; // log2(e)/sqrt(32)
    u16 h[8];
    #pragma unroll
    for (int i = 0; i < 8; i++) h[i] = f2bf(v[i] * scale);

    __shared__ u16 vt[32][72];  // padded transpose tile

    if (mat < 2) {
        u16* dst = ((mat == 0) ? qb : kb) + (size_t)b * NNK + j;
        u16x8 hv;
        #pragma unroll
        for (int i = 0; i < 8; i++) hv[i] = h[i];
        *(u16x8*)dst = hv;
    } else {
        const int n  = t >> 2;          // 0..63 local point
        const int k0 = (t & 3) * 8;     // feature start
        #pragma unroll
        for (int i = 0; i < 8; i++) vt[k0 + i][n] = h[i];
        __syncthreads();
        const int k  = t >> 3;          // 0..31
        const int c8 = t & 7;           // 0..7
        u16x8 ov;
        #pragma unroll
        for (int i = 0; i < 8; i++) ov[i] = vt[k][c8 * 8 + i];
        u16* dst = vT + (size_t)b * NNK + (size_t)k * NN + jc * 64 + c8 * 8;
        *(u16x8*)dst = ov;
    }
}

// ---------------- Kernel 3: fused flash attention + output/ori projection --------
// grid (32, 16), block 256 (4 waves x 16 q-rows). KVBLK=64.
// R7 rewrite: attn was LDS-pipe bound (~16 ds_bpermute/iter/wave for the P
// redistribution + K staged through LDS ~ 280 LDS-cyc/wave/iter ~ 30us).
// Now: (a) K fragments live in REGISTERS (coalesced 16B global loads, L2-hot,
// double-buffered) -- no K LDS traffic at all; (b) P goes through a per-wave
// padded LDS tile: 4x ds_write_b64 + 2x ds_read_b128 reconstruct the exact
// PV B-fragment (k=(l>>4)*8+e, col=n) -- replaces 16 bpermutes.
__global__ __launch_bounds__(256) void attn_kernel(
    const u16* __restrict__ qb, const u16* __restrict__ kb,
    const u16* __restrict__ vT,
    const float* __restrict__ Wout, const float* __restrict__ bout,
    const float* __restrict__ Wori, const float* __restrict__ bori,
    float* __restrict__ out)
{
    const int t = threadIdx.x;
    const int w = t >> 6;
    const int l = t & 63;
    const int g = l >> 4;
    const int n = l & 15;
    const int b = blockIdx.y;
    const int q0 = blockIdx.x * 64;

    __shared__ __align__(16) u16 Vs[2][2048];   // [32 dk][64 kv], col16 XOR-swizzled
    __shared__ __align__(16) u32 Pt[4][16][36]; // per-wave P tile, padded rows

    // Q fragment (B-operand of swapped QK^T): row q0+w*16+n, k = g*8..g*8+7
    const u16* qrow = qb + (size_t)b * NNK + (size_t)(q0 + w * 16 + n) * NKF + g * 8;
    const s8v qf = *(const s8v*)qrow;

    // K fragment base: lane (g,n) reads K[kv0 + n + 16tt][g*8..+7] per tt
    const u16* kbase = kb + (size_t)b * NNK + (size_t)n * NKF + g * 8;
    auto loadK = [&](s8v (&ka)[4], int it) {
        #pragma unroll
        for (int tt = 0; tt < 4; tt++)
            ka[tt] = *(const s8v*)(kbase + (size_t)it * 2048 + tt * 512);
    };

    // V staging (unchanged): [dk][kv] with col16 XOR swizzle, via regs
    const int vrow = t >> 3, vslot = t & 7;
    const int vcolL = (vslot ^ (vrow & 7)) * 8;   // pre-swizzled global column
    const u16* vgp = vT + (size_t)b * NNK + (size_t)vrow * NN + vcolL;

    s8v ka0[4], ka1[4], vreg;
    loadK(ka0, 0);
    vreg = *(const s8v*)(vgp);
    *(s8v*)(&Vs[0][t * 8]) = vreg;               // V tile 0 -> LDS buf0
    vreg = *(const s8v*)(vgp + 64);              // V tile 1 -> regs
    __syncthreads();

    float m_run = -INFINITY, l_run = 0.f;
    f4v O0 = {0.f, 0.f, 0.f, 0.f}, O1 = {0.f, 0.f, 0.f, 0.f};

    auto body = [&](s8v (&kc_)[4], s8v (&kn_)[4], int it) {
        const int cur = it & 1;
        if (it + 1 < 32) {   // stage V tile it+1; prefetch K frags it+1
            *(s8v*)(&Vs[cur ^ 1][t * 8]) = vreg;
            loadK(kn_, it + 1);
        }
        if (it + 2 < 32)     // prefetch V tile it+2 into regs
            vreg = *(const s8v*)(vgp + (size_t)(it + 2) * 64);

        // ---- QK^T (swapped), K from registers ----
        f4v S[4];
        #pragma unroll
        for (int tt = 0; tt < 4; tt++) {
            f4v z = {0.f, 0.f, 0.f, 0.f};
            S[tt] = __builtin_amdgcn_mfma_f32_16x16x32_bf16(kc_[tt], qf, z, 0, 0, 0);
        }

        // ---- online softmax in base-2 (scale folded into k) ----
        float pmax = -INFINITY;
        #pragma unroll
        for (int tt = 0; tt < 4; tt++)
            #pragma unroll
            for (int r = 0; r < 4; r++) pmax = fmaxf(pmax, S[tt][r]);
        pmax = fmaxf(pmax, __shfl_xor(pmax, 16));
        pmax = fmaxf(pmax, __shfl_xor(pmax, 32));
        const float m_new = fmaxf(m_run, pmax);
        const float corr = exp2f(m_run - m_new);

        float p[4][4];
        float tsum = 0.f;
        #pragma unroll
        for (int tt = 0; tt < 4; tt++)
            #pragma unroll
            for (int r = 0; r < 4; r++) {
                p[tt][r] = exp2f(S[tt][r] - m_new);
                tsum += p[tt][r];
            }
        tsum += __shfl_xor(tsum, 16);
        tsum += __shfl_xor(tsum, 32);
        l_run = l_run * corr + tsum;
        m_run = m_new;
        #pragma unroll
        for (int r = 0; r < 4; r++) { O0[r] *= corr; O1[r] *= corr; }

        // ---- P -> per-wave LDS tile: word (kv/2) = 8tt+2g+j at row n ----
        #pragma unroll
        for (int tt = 0; tt < 4; tt++) {
            u32 w0 = (u32)f2bf(p[tt][0]) | ((u32)f2bf(p[tt][1]) << 16);
            u32 w1 = (u32)f2bf(p[tt][2]) | ((u32)f2bf(p[tt][3]) << 16);
            *(uint2*)&Pt[w][n][8 * tt + 2 * g] = make_uint2(w0, w1);
        }

        // ---- PV: read own B-fragment back (k = 8g+e, col = n), 2 kc-chunks ----
        #pragma unroll
        for (int kc = 0; kc < 2; kc++) {
            u32x4 pw = *(const u32x4*)&Pt[w][n][16 * kc + 4 * g];
            s8v pa = __builtin_bit_cast(s8v, pw);
            {   // dt = 0
                int row = n;
                int slot = (g + 4 * kc) ^ (row & 7);
                s8v va = *(const s8v*)(&Vs[cur][row * 64 + slot * 8]);
                O0 = __builtin_amdgcn_mfma_f32_16x16x32_bf16(va, pa, O0, 0, 0, 0);
            }
            {   // dt = 1
                int row = n + 16;
                int slot = (g + 4 * kc) ^ (row & 7);
                s8v va = *(const s8v*)(&Vs[cur][row * 64 + slot * 8]);
                O1 = __builtin_amdgcn_mfma_f32_16x16x32_bf16(va, pa, O1, 0, 0, 0);
            }
        }
        __syncthreads();
    };

    #pragma unroll 1
    for (int i2 = 0; i2 < 16; i2++) {
        body(ka0, ka1, 2 * i2);
        body(ka1, ka0, 2 * i2 + 1);
    }

    // ---- epilogue: out = O/l * Wout^T + q * Wori^T + bout + bori ----
    const float inv = 1.0f / l_run;
    float po[3] = {0.f, 0.f, 0.f};
    #pragma unroll
    for (int r = 0; r < 4; r++) {
        int dk0 = 4 * g + r;
        int dk1 = 16 + 4 * g + r;
        float o0 = O0[r] * inv;
        float o1 = O1[r] * inv;
        #pragma unroll
        for (int c = 0; c < 3; c++) {
            po[c] += o0 * Wout[c * NKF + dk0];
            po[c] += o1 * Wout[c * NKF + dk1];
        }
    }
    #pragma unroll
    for (int e = 0; e < 8; e++) {
        float qv = bf2f((u16)qf[e]);
        int k = 8 * g + e;
        #pragma unroll
        for (int c = 0; c < 3; c++) po[c] += qv * Wori[c * NKF + k];
    }
    #pragma unroll
    for (int c = 0; c < 3; c++) {
        po[c] += __shfl_xor(po[c], 16);
        po[c] += __shfl_xor(po[c], 32);
    }
    if (g == 0) {
        int row = q0 + w * 16 + n;
        size_t o = ((size_t)b * NN + row) * 3;
        #pragma unroll
        for (int c = 0; c < 3; c++) out[o + c] = po[c] + bout[c] + bori[c];
    }
}

// ---------------- launch ----------------
extern "C" void kernel_launch(void* const* d_in, const int* in_sizes, int n_in,
                              void* d_out, int out_size, void* d_ws, size_t ws_size,
                              hipStream_t stream) {
    const float* x    = (const float*)d_in[0];
    const float* WQ   = (const float*)d_in[1];
    const float* bQ   = (const float*)d_in[2];
    const float* WK   = (const float*)d_in[3];
    const float* bK   = (const float*)d_in[4];
    const float* WV   = (const float*)d_in[5];
    const float* bV   = (const float*)d_in[6];
    const float* Wout = (const float*)d_in[7];
    const float* bout = (const float*)d_in[8];
    const float* Wori = (const float*)d_in[9];
    const float* bori = (const float*)d_in[10];
    float* out = (float*)d_out;

    char* ws = (char*)d_ws;
    u16* part = (u16*)ws;                              // 3*4*16*65536*2 = 25165824 B
    u16* qb = (u16*)(ws + 25165824);                   // 2 MB
    u16* kb = (u16*)(ws + 25165824 + 2097152);         // 2 MB
    u16* vT = (u16*)(ws + 25165824 + 2 * 2097152);     // 2 MB

    proj_partial<<<dim3(64, 3, 4), 256, 0, stream>>>(x, WQ, WK, WV, part);
    reduce_cast<<<dim3(32, 16, 3), 256, 0, stream>>>(part, bQ, bK, bV, qb, kb, vT);
    attn_kernel<<<dim3(32, 16), 256, 0, stream>>>(qb, kb, vT, Wout, bout, Wori, bori, out);
}